// Round 2
// baseline (249.051 us; speedup 1.0000x reference)
//
#include <hip/hip_runtime.h>

// Problem: B=16, LX=2048, LR=1024, D=768, T=LX+LR+3=3075
// out[b,t,:] =
//   t==0                       -> CLS
//   1 <= t <= lx[b]            -> X[b, t-1, :]
//   t == lx[b]+1               -> RING
//   lx[b]+2 <= t < lx[b]+2+lr  -> Xr[b, t-lx[b]-2, :]
//   t == lx[b]+lr[b]+2         -> END
//   else                       -> 0
//
// R5b (resubmit of R5; round-1 bench was an infra flake, no counters):
// 8 rows per 192-thread block, 2D grid (t-tile, b).
//  - b is block-uniform -> one scalar lx/lr load per block (was: per row,
//    after an integer divide).
//  - #pragma unroll 8 -> 8 independent nontemporal float4 loads in flight
//    per lane before the first dependent store (8x the memory-level
//    parallelism of the one-row-per-block R4 kernel).
//  - 6160 blocks instead of 49200 -> 8x less kernarg/preamble overhead.
// Branches remain block-uniform (t, lx, lr uniform) -> pure scalar control
// flow, zero divergence. NT load/store on streaming tensors (X, Xr, out);
// CLS/RING/END stay cached (reused by every block).

constexpr int B_  = 16;
constexpr int LX_ = 2048;
constexpr int LR_ = 1024;
constexpr int D_  = 768;
constexpr int T_  = LX_ + LR_ + 3;           // 3075
constexpr int RPB = 8;                       // rows (t values) per block
constexpr int NTL = (T_ + RPB - 1) / RPB;    // 385 t-tiles (last has 3 rows)

typedef float vfloat4 __attribute__((ext_vector_type(4)));

__global__ __launch_bounds__(192)
void assemble_rows_kernel(const float* __restrict__ X,
                          const float* __restrict__ Xr,
                          const float* __restrict__ CLS,
                          const float* __restrict__ RING,
                          const float* __restrict__ END,
                          const int* __restrict__ lx,
                          const int* __restrict__ lr,
                          float* __restrict__ out)
{
    const int b   = blockIdx.y;              // uniform
    const int t0  = blockIdx.x * RPB;        // uniform
    const int lxb = lx[b];                   // uniform -> s_load
    const int lrb = lr[b];
    const int doff = threadIdx.x * 4;        // float offset within row

    const float* __restrict__ Xb   = X  + ((size_t)b * LX_) * D_ + doff;
    const float* __restrict__ Xrb  = Xr + ((size_t)b * LR_) * D_ + doff;
    float* __restrict__ outp = out + ((size_t)b * T_ + t0) * D_ + doff;

    vfloat4 v[RPB];

    #pragma unroll
    for (int i = 0; i < RPB; ++i) {
        const int t = t0 + i;
        v[i] = (vfloat4)(0.f);
        if (t >= T_) continue;               // tail tile only
        if (t == 0) {
            v[i] = *reinterpret_cast<const vfloat4*>(CLS + doff);
        } else if (t <= lxb) {
            v[i] = __builtin_nontemporal_load(
                reinterpret_cast<const vfloat4*>(Xb + (size_t)(t - 1) * D_));
        } else if (t == lxb + 1) {
            v[i] = *reinterpret_cast<const vfloat4*>(RING + doff);
        } else if (t < lxb + 2 + lrb) {
            v[i] = __builtin_nontemporal_load(
                reinterpret_cast<const vfloat4*>(Xrb + (size_t)(t - lxb - 2) * D_));
        } else if (t == lxb + lrb + 2) {
            v[i] = *reinterpret_cast<const vfloat4*>(END + doff);
        }
    }

    #pragma unroll
    for (int i = 0; i < RPB; ++i) {
        if (t0 + i < T_) {
            __builtin_nontemporal_store(v[i],
                reinterpret_cast<vfloat4*>(outp + (size_t)i * D_));
        }
    }
}

extern "C" void kernel_launch(void* const* d_in, const int* in_sizes, int n_in,
                              void* d_out, int out_size, void* d_ws, size_t ws_size,
                              hipStream_t stream)
{
    const float* X    = (const float*)d_in[0];
    const float* Xr   = (const float*)d_in[1];
    const float* CLS  = (const float*)d_in[2];
    const float* RING = (const float*)d_in[3];
    const float* END  = (const float*)d_in[4];
    const int* lx = (const int*)d_in[5];
    const int* lr = (const int*)d_in[6];
    float* out = (float*)d_out;

    hipLaunchKernelGGL(assemble_rows_kernel, dim3(NTL, B_), dim3(192), 0, stream,
                       X, Xr, CLS, RING, END, lx, lr, out);
}